// Round 4
// baseline (634.504 us; speedup 1.0000x reference)
//
#include <hip/hip_runtime.h>

typedef __attribute__((ext_vector_type(4))) float floatx4;
typedef __attribute__((ext_vector_type(8))) short bf16x8;

__device__ __forceinline__ unsigned short f2bf(float f) {
    union { float f; unsigned u; } v; v.f = f;
    unsigned r = v.u + 0x7fffu + ((v.u >> 16) & 1u);  // RNE
    return (unsigned short)(r >> 16);
}

// ---------------------------------------------------------------------------
// prep: pack weights into MFMA B-operand fragment blobs (bf16) + fuse biases.
// Wcat blob [kc=0..47][ntg=0..31][lane=0..63][j=0..7]:
//   element B[k][n], k = kc*32 + (lane>>4)*8 + j, n = ntg*16 + (lane&15)
//   k < 1024 -> W1[c][k][s] (c=n>>5, s=n&31), else W2[c][k-1024][s]
// W3 blob   [kc=0..15][ntg=0..31][lane][j]: B[k][n] = W3flat[k*512 + n]
// bias12[n] = b1flat[n] + b2flat[n];  bias3s[n] = sum_c b3[c*512+n]
// ---------------------------------------------------------------------------
__global__ void prep_kernel(const float* __restrict__ W1, const float* __restrict__ b1,
                            const float* __restrict__ W2, const float* __restrict__ b2,
                            const float* __restrict__ W3, const float* __restrict__ b3,
                            unsigned short* __restrict__ wcat, unsigned short* __restrict__ w3f,
                            float* __restrict__ bias12, float* __restrict__ bias3s)
{
    int tid = blockIdx.x * 256 + threadIdx.x;
    if (tid < 98304) {                       // 48 * 32 * 64 fragment-lanes
        int l  = tid & 63;
        int nt = (tid >> 6) & 31;
        int kc = tid >> 11;                  // 0..47
        int n  = nt * 16 + (l & 15);
        int k0 = kc * 32 + ((l >> 4) << 3);
        int c = n >> 5, s = n & 31;
        union { unsigned short us[8]; int4 v; } pk;
        const float* src = (k0 < 1024) ? (W1 + c * 32768 + k0 * 32 + s)
                                       : (W2 + c * 16384 + (k0 - 1024) * 32 + s);
        #pragma unroll
        for (int j = 0; j < 8; ++j) pk.us[j] = f2bf(src[j * 32]);
        *(int4*)(wcat + (size_t)tid * 8) = pk.v;
    } else if (tid < 131072) {               // 16 * 32 * 64 fragment-lanes for W3
        int t  = tid - 98304;
        int l  = t & 63;
        int nt = (t >> 6) & 31;
        int kc = t >> 11;                    // 0..15
        int n  = nt * 16 + (l & 15);
        int k0 = kc * 32 + ((l >> 4) << 3);
        union { unsigned short us[8]; int4 v; } pk;
        const float* src = W3 + k0 * 512 + n;
        #pragma unroll
        for (int j = 0; j < 8; ++j) pk.us[j] = f2bf(src[j * 512]);
        *(int4*)(w3f + (size_t)t * 8) = pk.v;
    } else if (tid < 131584) {
        int n = tid - 131072;
        bias12[n] = b1[n] + b2[n];
        float sacc = 0.f;
        #pragma unroll
        for (int c = 0; c < 16; ++c) sacc += b3[c * 512 + n];
        bias3s[n] = sacc;
    }
}

// ---------------------------------------------------------------------------
// fused main: 64 rows/block, 512 threads = 8 waves, wave w owns cols
// [w*64, w*64+64). BK=64 periods (24 in phase 1), one raw barrier each
// (lgkmcnt(0) only; vmcnt survives the barrier). Changes vs R3:
//  - FULL-PERIOD A-prefetch, zero extra regs: chunk p+1 (loaded at top of
//    p-1) is staged at the TOP of period p into As[(p+1)&1] (that buffer's
//    reads were drained by the barrier ending p-1); the load of chunk p+2
//    is issued right after. In-flight window ~1 full period >= HBM
//    latency + delivery, so the staging vmcnt wait ~0.
//  - As XOR swizzle (slot ^= row within each 1024B fragment region, slot =
//    16B, row = 128B) kills the 8-way staging-write bank conflict while
//    keeping reads 2-way (free). Same permutation on write + read.
//  - bcur[0..3] for p+1 reloaded between the MFMA halves, bcur[4..7] after
//    half 1 (counted vmcnt at next use, crossing the barrier).
// LDS: As (16 KB) unioned over head of Hf (64 KB) -> 65536 B, 2 blocks/CU.
// MFMA 16x16x32 bf16; A-frag: lane l holds A[m=l&15][k=(l>>4)*8+j];
// B-frag: B[k=(l>>4)*8+j][n=l&15]; C/D: col=l&15, row=(l>>4)*4+reg.
// ---------------------------------------------------------------------------
__global__ __launch_bounds__(512, 4) void fused_main(
    const float* __restrict__ app, const float* __restrict__ sp,
    const unsigned short* __restrict__ wcat, const unsigned short* __restrict__ w3f,
    const float* __restrict__ bias12, const float* __restrict__ bias3s,
    float* __restrict__ out)
{
    __shared__ union {
        unsigned short As[2][2][4][64][8];   // 16 KB: [buf][half][mt][lane][j]
        unsigned short Hf[4][16][64][8];     // 64 KB: [mt][kc][lane][j]
    } sh;

    const int tid = (int)threadIdx.x;
    const int w   = tid >> 6;                 // 0..7
    const int l   = tid & 63;
    const int rowbase = (int)blockIdx.x * 64;

    // staging map: thread (sr, kq) holds row sr, k = period*64 + kq*8 .. +7
    const int sr = tid >> 3;                  // 0..63
    const int kq = tid & 7;                   // 0..7
    const float* appsrc = app + (size_t)(rowbase + sr) * 1024 + kq * 8;
    const float* spsrc  = sp  + (size_t)(rowbase + sr) * 512  + kq * 8;

    // swizzled write offset: region (half=kq>>2, mt=sr>>4), frag-lane
    // L = (kq&3)*16 + (sr&15); row = L>>3 (128B), slot = L&7 (16B); slot ^= row
    {
    }
    const int halfw = kq >> 2, mtw = sr >> 4;
    const int Lw    = ((kq & 3) << 4) + (sr & 15);
    const int roww  = Lw >> 3, slotw = Lw & 7;
    const int wroff = halfw * 4096 + mtw * 1024 + roww * 128 + ((slotw ^ roww) << 4);
    char* shb = (char*)&sh;
    unsigned short* as0 = (unsigned short*)(shb + wroff);           // buf 0
    unsigned short* as1 = (unsigned short*)(shb + 8192 + wroff);    // buf 1

    // swizzled read offset (per lane, same in every region): row=l>>3, slot=l&7
    const int rdoff = ((l >> 3) << 7) + (((l & 7) ^ (l >> 3)) << 4);
    #define AS_RD(buf, half, mt) \
        (*(const bf16x8*)(shb + (buf) * 8192 + (half) * 4096 + (mt) * 1024 + rdoff))

    floatx4 acc[4][4];
    #pragma unroll
    for (int mt = 0; mt < 4; ++mt)
        #pragma unroll
        for (int nt = 0; nt < 4; ++nt)
            acc[mt][nt] = (floatx4){0.f, 0.f, 0.f, 0.f};

    const unsigned short* wbase = wcat + (size_t)w * 2048 + (size_t)l * 8;

    // prologue: load chunk 0 + chunk 1, B-frags for period 0; stage chunk 0
    float4 c00 = *(const float4*)(appsrc);
    float4 c01 = *(const float4*)(appsrc + 4);
    float4 pA0 = *(const float4*)(appsrc + 64);   // chunk 1
    float4 pA1 = *(const float4*)(appsrc + 68);
    bf16x8 bcur[8];
    #pragma unroll
    for (int i = 0; i < 8; ++i)
        bcur[i] = *(const bf16x8*)(wbase + (i >> 2) * 16384 + (i & 3) * 512);
    {
        union { unsigned short us[8]; int4 v; } pk;
        pk.us[0] = f2bf(c00.x); pk.us[1] = f2bf(c00.y); pk.us[2] = f2bf(c00.z); pk.us[3] = f2bf(c00.w);
        pk.us[4] = f2bf(c01.x); pk.us[5] = f2bf(c01.y); pk.us[6] = f2bf(c01.z); pk.us[7] = f2bf(c01.w);
        *(int4*)as0 = pk.v;
    }
    asm volatile("s_waitcnt lgkmcnt(0)" ::: "memory");
    __builtin_amdgcn_s_barrier();

    // ---- phase 1: H_pre = [app|sp] @ Wcat, K = 1536 (24 periods of 64) ----
    for (int p = 0; p < 24; ++p) {
        const int buf = p & 1;

        // stage chunk p+1 (load issued one full period ago) into As[(p+1)&1]
        if (p + 1 < 24) {
            union { unsigned short us[8]; int4 v; } pk;
            pk.us[0] = f2bf(pA0.x); pk.us[1] = f2bf(pA0.y); pk.us[2] = f2bf(pA0.z); pk.us[3] = f2bf(pA0.w);
            pk.us[4] = f2bf(pA1.x); pk.us[5] = f2bf(pA1.y); pk.us[6] = f2bf(pA1.z); pk.us[7] = f2bf(pA1.w);
            *(int4*)((buf == 0) ? as1 : as0) = pk.v;
        }
        // issue HBM load for chunk p+2 (staged at top of next period)
        if (p + 2 < 24) {
            const int c = p + 2;
            const float* src = (c < 16) ? (appsrc + c * 64) : (spsrc + (c - 16) * 64);
            pA0 = *(const float4*)src;
            pA1 = *(const float4*)(src + 4);
        }

        bf16x8 af[4];
        // half 0 (k = p*64 .. +31)
        #pragma unroll
        for (int mt = 0; mt < 4; ++mt)
            af[mt] = AS_RD(buf, 0, mt);
        __builtin_amdgcn_s_setprio(1);
        #pragma unroll
        for (int mt = 0; mt < 4; ++mt)
            #pragma unroll
            for (int nt = 0; nt < 4; ++nt)
                acc[mt][nt] = __builtin_amdgcn_mfma_f32_16x16x32_bf16(
                    af[mt], bcur[nt], acc[mt][nt], 0, 0, 0);
        __builtin_amdgcn_s_setprio(0);
        // reload bcur[0..3] for p+1 (in flight across half1 + barrier + stage)
        const unsigned short* wp = wbase + (size_t)(p + 1) * 32768;
        if (p + 1 < 24) {
            #pragma unroll
            for (int i = 0; i < 4; ++i)
                bcur[i] = *(const bf16x8*)(wp + i * 512);
        }
        // half 1 (k = p*64+32 .. +63)
        #pragma unroll
        for (int mt = 0; mt < 4; ++mt)
            af[mt] = AS_RD(buf, 1, mt);
        __builtin_amdgcn_s_setprio(1);
        #pragma unroll
        for (int mt = 0; mt < 4; ++mt)
            #pragma unroll
            for (int nt = 0; nt < 4; ++nt)
                acc[mt][nt] = __builtin_amdgcn_mfma_f32_16x16x32_bf16(
                    af[mt], bcur[4 + nt], acc[mt][nt], 0, 0, 0);
        __builtin_amdgcn_s_setprio(0);
        // reload bcur[4..7] for p+1
        if (p + 1 < 24) {
            #pragma unroll
            for (int i = 0; i < 4; ++i)
                bcur[4 + i] = *(const bf16x8*)(wp + 16384 + i * 512);
        }

        asm volatile("s_waitcnt lgkmcnt(0)" ::: "memory");
        __builtin_amdgcn_s_barrier();
    }

    // ---- phase-3 W3 prefetch (before phase-2 writes; vmcnt survives) ----
    const unsigned short* w3base = w3f + (size_t)w * 2048 + (size_t)l * 8;
    bf16x8 b3[8];
    #pragma unroll
    for (int i = 0; i < 8; ++i)
        b3[i] = *(const bf16x8*)(w3base + (i >> 2) * 16384 + (i & 3) * 512);

    // ---- phase 2: relu + bias, write Hf in A-frag layout (clobbers As) ----
    #pragma unroll
    for (int nt = 0; nt < 4; ++nt) {
        const int colg = w * 64 + nt * 16 + (l & 15);
        const float bv = bias12[colg];
        const int kc  = colg >> 5;
        const int lhi = ((colg >> 3) & 3) << 4;
        const int j   = colg & 7;
        #pragma unroll
        for (int mt = 0; mt < 4; ++mt)
            #pragma unroll
            for (int r = 0; r < 4; ++r) {
                const int rlow = ((l >> 4) << 2) + r;      // rowg & 15
                float v = acc[mt][nt][r] + bv;
                v = fmaxf(v, 0.f);
                sh.Hf[mt][kc][lhi + rlow][j] = f2bf(v);
            }
    }
    asm volatile("s_waitcnt lgkmcnt(0)" ::: "memory");
    __builtin_amdgcn_s_barrier();

    // ---- phase 3: out = relu(Hf @ W3 + bias3s), K = 512, NO barriers ----
    #pragma unroll
    for (int mt = 0; mt < 4; ++mt)
        #pragma unroll
        for (int nt = 0; nt < 4; ++nt)
            acc[mt][nt] = (floatx4){0.f, 0.f, 0.f, 0.f};

    for (int q = 0; q < 8; ++q) {
        bf16x8 af[4];
        #pragma unroll
        for (int mt = 0; mt < 4; ++mt)
            af[mt] = *(const bf16x8*)(&sh.Hf[mt][2 * q][l][0]);
        __builtin_amdgcn_s_setprio(1);
        #pragma unroll
        for (int mt = 0; mt < 4; ++mt)
            #pragma unroll
            for (int nt = 0; nt < 4; ++nt)
                acc[mt][nt] = __builtin_amdgcn_mfma_f32_16x16x32_bf16(
                    af[mt], b3[nt], acc[mt][nt], 0, 0, 0);
        __builtin_amdgcn_s_setprio(0);
        #pragma unroll
        for (int mt = 0; mt < 4; ++mt)
            af[mt] = *(const bf16x8*)(&sh.Hf[mt][2 * q + 1][l][0]);
        __builtin_amdgcn_s_setprio(1);
        #pragma unroll
        for (int mt = 0; mt < 4; ++mt)
            #pragma unroll
            for (int nt = 0; nt < 4; ++nt)
                acc[mt][nt] = __builtin_amdgcn_mfma_f32_16x16x32_bf16(
                    af[mt], b3[4 + nt], acc[mt][nt], 0, 0, 0);
        __builtin_amdgcn_s_setprio(0);
        if (q + 1 < 8) {
            const unsigned short* wp = w3base + (size_t)(q + 1) * 32768;
            #pragma unroll
            for (int i = 0; i < 8; ++i)
                b3[i] = *(const bf16x8*)(wp + (i >> 2) * 16384 + (i & 3) * 512);
        }
    }

    // ---- epilogue ----
    #pragma unroll
    for (int nt = 0; nt < 4; ++nt) {
        const int colg = w * 64 + nt * 16 + (l & 15);
        const float bv = bias3s[colg];
        #pragma unroll
        for (int mt = 0; mt < 4; ++mt)
            #pragma unroll
            for (int r = 0; r < 4; ++r) {
                const int rowg = mt * 16 + ((l >> 4) << 2) + r;
                float v = acc[mt][nt][r] + bv;
                v = fmaxf(v, 0.f);
                out[(size_t)(rowbase + rowg) * 512 + colg] = v;
            }
    }
    #undef AS_RD
}

extern "C" void kernel_launch(void* const* d_in, const int* in_sizes, int n_in,
                              void* d_out, int out_size, void* d_ws, size_t ws_size,
                              hipStream_t stream)
{
    const float* app = (const float*)d_in[0];
    const float* sp  = (const float*)d_in[1];
    const float* W1  = (const float*)d_in[2];
    const float* b1  = (const float*)d_in[3];
    const float* W2  = (const float*)d_in[4];
    const float* b2  = (const float*)d_in[5];
    const float* W3  = (const float*)d_in[6];
    const float* b3  = (const float*)d_in[7];

    char* ws = (char*)d_ws;
    unsigned short* wcat  = (unsigned short*)(ws);             // 1,572,864 B
    unsigned short* w3f   = (unsigned short*)(ws + 1572864);   //   524,288 B
    float*          b12   = (float*)(ws + 2097152);            //     2,048 B
    float*          b3s   = (float*)(ws + 2099200);            //     2,048 B

    prep_kernel<<<514, 256, 0, stream>>>(W1, b1, W2, b2, W3, b3, wcat, w3f, b12, b3s);

    float* outp = (float*)d_out;
    fused_main<<<65536 / 64, 512, 0, stream>>>(app, sp, wcat, w3f, b12, b3s, outp);
}

// Round 5
// 545.491 us; speedup vs baseline: 1.1632x; 1.1632x over previous
//
#include <hip/hip_runtime.h>

typedef __attribute__((ext_vector_type(4))) float floatx4;
typedef __attribute__((ext_vector_type(8))) short bf16x8;

__device__ __forceinline__ unsigned short f2bf(float f) {
    union { float f; unsigned u; } v; v.f = f;
    unsigned r = v.u + 0x7fffu + ((v.u >> 16) & 1u);  // RNE
    return (unsigned short)(r >> 16);
}

// ---------------------------------------------------------------------------
// prep: pack weights into MFMA B-operand fragment blobs (bf16) + fuse biases.
// Wcat blob [kc=0..47][ntg=0..31][lane=0..63][j=0..7]:
//   element B[k][n], k = kc*32 + (lane>>4)*8 + j, n = ntg*16 + (lane&15)
//   k < 1024 -> W1[c][k][s] (c=n>>5, s=n&31), else W2[c][k-1024][s]
// W3 blob   [kc=0..15][ntg=0..31][lane][j]: B[k][n] = W3flat[k*512 + n]
// bias12[n] = b1flat[n] + b2flat[n];  bias3s[n] = sum_c b3[c*512+n]
// ---------------------------------------------------------------------------
__global__ void prep_kernel(const float* __restrict__ W1, const float* __restrict__ b1,
                            const float* __restrict__ W2, const float* __restrict__ b2,
                            const float* __restrict__ W3, const float* __restrict__ b3,
                            unsigned short* __restrict__ wcat, unsigned short* __restrict__ w3f,
                            float* __restrict__ bias12, float* __restrict__ bias3s)
{
    int tid = blockIdx.x * 256 + threadIdx.x;
    if (tid < 98304) {                       // 48 * 32 * 64 fragment-lanes
        int l  = tid & 63;
        int nt = (tid >> 6) & 31;
        int kc = tid >> 11;                  // 0..47
        int n  = nt * 16 + (l & 15);
        int k0 = kc * 32 + ((l >> 4) << 3);
        int c = n >> 5, s = n & 31;
        union { unsigned short us[8]; int4 v; } pk;
        const float* src = (k0 < 1024) ? (W1 + c * 32768 + k0 * 32 + s)
                                       : (W2 + c * 16384 + (k0 - 1024) * 32 + s);
        #pragma unroll
        for (int j = 0; j < 8; ++j) pk.us[j] = f2bf(src[j * 32]);
        *(int4*)(wcat + (size_t)tid * 8) = pk.v;
    } else if (tid < 131072) {               // 16 * 32 * 64 fragment-lanes for W3
        int t  = tid - 98304;
        int l  = t & 63;
        int nt = (t >> 6) & 31;
        int kc = t >> 11;                    // 0..15
        int n  = nt * 16 + (l & 15);
        int k0 = kc * 32 + ((l >> 4) << 3);
        union { unsigned short us[8]; int4 v; } pk;
        const float* src = W3 + k0 * 512 + n;
        #pragma unroll
        for (int j = 0; j < 8; ++j) pk.us[j] = f2bf(src[j * 512]);
        *(int4*)(w3f + (size_t)t * 8) = pk.v;
    } else if (tid < 131584) {
        int n = tid - 131072;
        bias12[n] = b1[n] + b2[n];
        float sacc = 0.f;
        #pragma unroll
        for (int c = 0; c < 16; ++c) sacc += b3[c * 512 + n];
        bias3s[n] = sacc;
    }
}

// ---------------------------------------------------------------------------
// fused main: 64 rows/block, 512 threads = 8 waves, wave w owns cols
// [w*64, w*64+64). BK=64 periods (24 in phase 1), one raw barrier each
// (lgkmcnt(0) only; vmcnt survives the barrier).
// == R3 schedule EXACTLY (known no-spill, 211 us) + XOR swizzle on As ==
//  - A-chunk for p+1: HBM load issued at TOP of period p (registers),
//    staged into the other As buffer at the TAIL of period p. In-flight
//    window ~ one full period. pA liveness = within one period (no spill).
//  - all 8 B-frags for p+1 reloaded in one batch AFTER the MFMA clusters;
//    counted vmcnt at first use next period (crosses the barrier).
//  - As XOR swizzle (slot ^= row within each 1024B fragment region, slot =
//    16B, row = 128B): staging writes 2-way (free), reads 2-way (free).
//    Verified correct in R4 (passed, conflicts 12.1M -> 2.6M).
//  - phase 3: NO barriers (Hf read-only); W3 frags prefetched before the
//    phase-2 barrier.
// LDS: As (16 KB) unioned over head of Hf (64 KB) -> 65536 B, 2 blocks/CU.
// MFMA 16x16x32 bf16; A-frag: lane l holds A[m=l&15][k=(l>>4)*8+j];
// B-frag: B[k=(l>>4)*8+j][n=l&15]; C/D: col=l&15, row=(l>>4)*4+reg.
// ---------------------------------------------------------------------------
__global__ __launch_bounds__(512, 4) void fused_main(
    const float* __restrict__ app, const float* __restrict__ sp,
    const unsigned short* __restrict__ wcat, const unsigned short* __restrict__ w3f,
    const float* __restrict__ bias12, const float* __restrict__ bias3s,
    float* __restrict__ out)
{
    __shared__ union {
        unsigned short As[2][2][4][64][8];   // 16 KB: [buf][half][mt][lane][j]
        unsigned short Hf[4][16][64][8];     // 64 KB: [mt][kc][lane][j]
    } sh;

    const int tid = (int)threadIdx.x;
    const int w   = tid >> 6;                 // 0..7
    const int l   = tid & 63;
    const int rowbase = (int)blockIdx.x * 64;

    // staging map: thread (sr, kq) holds row sr, k = period*64 + kq*8 .. +7
    const int sr = tid >> 3;                  // 0..63
    const int kq = tid & 7;                   // 0..7
    const float* appsrc = app + (size_t)(rowbase + sr) * 1024 + kq * 8;
    const float* spsrc  = sp  + (size_t)(rowbase + sr) * 512  + kq * 8;

    // swizzled write offset: region (half=kq>>2, mt=sr>>4), frag-lane
    // L = (kq&3)*16 + (sr&15); row = L>>3 (128B), slot = L&7 (16B); slot ^= row
    const int halfw = kq >> 2, mtw = sr >> 4;
    const int Lw    = ((kq & 3) << 4) + (sr & 15);
    const int roww  = Lw >> 3, slotw = Lw & 7;
    const int wroff = halfw * 4096 + mtw * 1024 + roww * 128 + ((slotw ^ roww) << 4);
    char* shb = (char*)&sh;
    unsigned short* as0 = (unsigned short*)(shb + wroff);           // buf 0
    unsigned short* as1 = (unsigned short*)(shb + 8192 + wroff);    // buf 1

    // swizzled read offset (per lane, same in every region): row=l>>3, slot=l&7
    const int rdoff = ((l >> 3) << 7) + (((l & 7) ^ (l >> 3)) << 4);
    #define AS_RD(buf, half, mt) \
        (*(const bf16x8*)(shb + (buf) * 8192 + (half) * 4096 + (mt) * 1024 + rdoff))

    floatx4 acc[4][4];
    #pragma unroll
    for (int mt = 0; mt < 4; ++mt)
        #pragma unroll
        for (int nt = 0; nt < 4; ++nt)
            acc[mt][nt] = (floatx4){0.f, 0.f, 0.f, 0.f};

    const unsigned short* wbase = wcat + (size_t)w * 2048 + (size_t)l * 8;

    // prologue: stage chunk 0; load B-frags for period 0
    bf16x8 bcur[8];
    #pragma unroll
    for (int i = 0; i < 8; ++i)
        bcur[i] = *(const bf16x8*)(wbase + (i >> 2) * 16384 + (i & 3) * 512);
    {
        float4 q0 = *(const float4*)(appsrc);
        float4 q1 = *(const float4*)(appsrc + 4);
        union { unsigned short us[8]; int4 v; } pk;
        pk.us[0] = f2bf(q0.x); pk.us[1] = f2bf(q0.y); pk.us[2] = f2bf(q0.z); pk.us[3] = f2bf(q0.w);
        pk.us[4] = f2bf(q1.x); pk.us[5] = f2bf(q1.y); pk.us[6] = f2bf(q1.z); pk.us[7] = f2bf(q1.w);
        *(int4*)as0 = pk.v;
    }
    asm volatile("s_waitcnt lgkmcnt(0)" ::: "memory");
    __builtin_amdgcn_s_barrier();

    // ---- phase 1: H_pre = [app|sp] @ Wcat, K = 1536 (24 periods of 64) ----
    for (int p = 0; p < 24; ++p) {
        const int buf = p & 1;
        unsigned short* dst = buf ? as0 : as1;          // stage target (p+1)

        // issue HBM A-loads for period p+1 (consumed at tail of this period)
        float4 pA0, pA1;
        if (p + 1 < 24) {
            const float* src = (p + 1 < 16) ? (appsrc + (p + 1) * 64)
                                            : (spsrc + (p - 15) * 64);
            pA0 = *(const float4*)src;
            pA1 = *(const float4*)(src + 4);
        }

        bf16x8 af[4];
        // half 0 (k = p*64 .. +31)
        #pragma unroll
        for (int mt = 0; mt < 4; ++mt)
            af[mt] = AS_RD(buf, 0, mt);
        __builtin_amdgcn_s_setprio(1);
        #pragma unroll
        for (int mt = 0; mt < 4; ++mt)
            #pragma unroll
            for (int nt = 0; nt < 4; ++nt)
                acc[mt][nt] = __builtin_amdgcn_mfma_f32_16x16x32_bf16(
                    af[mt], bcur[nt], acc[mt][nt], 0, 0, 0);
        __builtin_amdgcn_s_setprio(0);
        // half 1 (k = p*64+32 .. +63)
        #pragma unroll
        for (int mt = 0; mt < 4; ++mt)
            af[mt] = AS_RD(buf, 1, mt);
        __builtin_amdgcn_s_setprio(1);
        #pragma unroll
        for (int mt = 0; mt < 4; ++mt)
            #pragma unroll
            for (int nt = 0; nt < 4; ++nt)
                acc[mt][nt] = __builtin_amdgcn_mfma_f32_16x16x32_bf16(
                    af[mt], bcur[4 + nt], acc[mt][nt], 0, 0, 0);
        __builtin_amdgcn_s_setprio(0);

        // batched B-frag reload for p+1 (in flight across tail+barrier+reads)
        if (p + 1 < 24) {
            const unsigned short* wp = wbase + (size_t)(p + 1) * 32768;
            #pragma unroll
            for (int i = 0; i < 8; ++i)
                bcur[i] = *(const bf16x8*)(wp + (i >> 2) * 16384 + (i & 3) * 512);
            // stage A chunk p+1 (waits only its own vmcnt, counted)
            union { unsigned short us[8]; int4 v; } pk;
            pk.us[0] = f2bf(pA0.x); pk.us[1] = f2bf(pA0.y); pk.us[2] = f2bf(pA0.z); pk.us[3] = f2bf(pA0.w);
            pk.us[4] = f2bf(pA1.x); pk.us[5] = f2bf(pA1.y); pk.us[6] = f2bf(pA1.z); pk.us[7] = f2bf(pA1.w);
            *(int4*)dst = pk.v;
        }

        asm volatile("s_waitcnt lgkmcnt(0)" ::: "memory");
        __builtin_amdgcn_s_barrier();
    }

    // ---- phase-3 W3 prefetch (before phase-2 writes; vmcnt survives) ----
    const unsigned short* w3base = w3f + (size_t)w * 2048 + (size_t)l * 8;
    bf16x8 b3[8];
    #pragma unroll
    for (int i = 0; i < 8; ++i)
        b3[i] = *(const bf16x8*)(w3base + (i >> 2) * 16384 + (i & 3) * 512);

    // ---- phase 2: relu + bias, write Hf in A-frag layout (clobbers As) ----
    #pragma unroll
    for (int nt = 0; nt < 4; ++nt) {
        const int colg = w * 64 + nt * 16 + (l & 15);
        const float bv = bias12[colg];
        const int kc  = colg >> 5;
        const int lhi = ((colg >> 3) & 3) << 4;
        const int j   = colg & 7;
        #pragma unroll
        for (int mt = 0; mt < 4; ++mt)
            #pragma unroll
            for (int r = 0; r < 4; ++r) {
                const int rlow = ((l >> 4) << 2) + r;      // rowg & 15
                float v = acc[mt][nt][r] + bv;
                v = fmaxf(v, 0.f);
                sh.Hf[mt][kc][lhi + rlow][j] = f2bf(v);
            }
    }
    asm volatile("s_waitcnt lgkmcnt(0)" ::: "memory");
    __builtin_amdgcn_s_barrier();

    // ---- phase 3: out = relu(Hf @ W3 + bias3s), K = 512, NO barriers ----
    #pragma unroll
    for (int mt = 0; mt < 4; ++mt)
        #pragma unroll
        for (int nt = 0; nt < 4; ++nt)
            acc[mt][nt] = (floatx4){0.f, 0.f, 0.f, 0.f};

    for (int q = 0; q < 8; ++q) {
        bf16x8 af[4];
        #pragma unroll
        for (int mt = 0; mt < 4; ++mt)
            af[mt] = *(const bf16x8*)(&sh.Hf[mt][2 * q][l][0]);
        __builtin_amdgcn_s_setprio(1);
        #pragma unroll
        for (int mt = 0; mt < 4; ++mt)
            #pragma unroll
            for (int nt = 0; nt < 4; ++nt)
                acc[mt][nt] = __builtin_amdgcn_mfma_f32_16x16x32_bf16(
                    af[mt], b3[nt], acc[mt][nt], 0, 0, 0);
        __builtin_amdgcn_s_setprio(0);
        #pragma unroll
        for (int mt = 0; mt < 4; ++mt)
            af[mt] = *(const bf16x8*)(&sh.Hf[mt][2 * q + 1][l][0]);
        __builtin_amdgcn_s_setprio(1);
        #pragma unroll
        for (int mt = 0; mt < 4; ++mt)
            #pragma unroll
            for (int nt = 0; nt < 4; ++nt)
                acc[mt][nt] = __builtin_amdgcn_mfma_f32_16x16x32_bf16(
                    af[mt], b3[4 + nt], acc[mt][nt], 0, 0, 0);
        __builtin_amdgcn_s_setprio(0);
        if (q + 1 < 8) {
            const unsigned short* wp = w3base + (size_t)(q + 1) * 32768;
            #pragma unroll
            for (int i = 0; i < 8; ++i)
                b3[i] = *(const bf16x8*)(wp + (i >> 2) * 16384 + (i & 3) * 512);
        }
    }

    // ---- epilogue ----
    #pragma unroll
    for (int nt = 0; nt < 4; ++nt) {
        const int colg = w * 64 + nt * 16 + (l & 15);
        const float bv = bias3s[colg];
        #pragma unroll
        for (int mt = 0; mt < 4; ++mt)
            #pragma unroll
            for (int r = 0; r < 4; ++r) {
                const int rowg = mt * 16 + ((l >> 4) << 2) + r;
                float v = acc[mt][nt][r] + bv;
                v = fmaxf(v, 0.f);
                out[(size_t)(rowbase + rowg) * 512 + colg] = v;
            }
    }
    #undef AS_RD
}

extern "C" void kernel_launch(void* const* d_in, const int* in_sizes, int n_in,
                              void* d_out, int out_size, void* d_ws, size_t ws_size,
                              hipStream_t stream)
{
    const float* app = (const float*)d_in[0];
    const float* sp  = (const float*)d_in[1];
    const float* W1  = (const float*)d_in[2];
    const float* b1  = (const float*)d_in[3];
    const float* W2  = (const float*)d_in[4];
    const float* b2  = (const float*)d_in[5];
    const float* W3  = (const float*)d_in[6];
    const float* b3  = (const float*)d_in[7];

    char* ws = (char*)d_ws;
    unsigned short* wcat  = (unsigned short*)(ws);             // 1,572,864 B
    unsigned short* w3f   = (unsigned short*)(ws + 1572864);   //   524,288 B
    float*          b12   = (float*)(ws + 2097152);            //     2,048 B
    float*          b3s   = (float*)(ws + 2099200);            //     2,048 B

    prep_kernel<<<514, 256, 0, stream>>>(W1, b1, W2, b2, W3, b3, wcat, w3f, b12, b3s);

    float* outp = (float*)d_out;
    fused_main<<<65536 / 64, 512, 0, stream>>>(app, sp, wcat, w3f, b12, b3s, outp);
}